// Round 5
// baseline (73.695 us; speedup 1.0000x reference)
//
#include <hip/hip_runtime.h>

// DistanceTransform closed form (verified absmax=0.0 in earlier rounds):
//   d(p)  = Chebyshev (L_inf) distance to nearest seed (replicate-pad => clamp)
//   out(p)= 0 if d==0 else (d-1) - 0.35*log(a*w1 + c*w2)
// where a/c = # edge/corner 3x3 taps whose CLAMPED source pixel has d < d(p),
// w1 = exp(-1/0.35), w2 = exp(-sqrt(2)/0.35).
//
// Round-8: single kernel, producer/consumer via ws flags — HARDENED.
// R4 (container died) likely faulted on untrusted ws: a separate count word
// could be garbage under a MAGIC-matching flag -> OOB slot reads + negative
// atomicAdd base -> LDS OOB write. Fixes:
//   - count is embedded in the flag word (0x5EED0000|pc) and clamped to 512
//   - every slist/slot access bounds-guarded; no value read from ws can cause
//     an access outside [ws, ws+257KB) or outside LDS arrays
//   - bounded spin (2048 polls + s_sleep) + self-scan fallback: correctness
//     never depends on dispatch order or co-residency (G16); stale-valid
//     flags re-publish identical bytes (same input) -> benign.
// Chebyshev chains + epilogue bit-identical to the absmax=0.0-verified R3.

#define RGX 34                  // 32 + 2 halo
#define RGY 18                  // 16 + 2 halo
#define RGSZ (RGX * RGY)        // 612
#define SEED_CAP 1024
#define NBLK 256
#define SLOT_BYTES 1024         // 512 ushort seeds max per 512-px segment
#define FLAGS_OFF (NBLK * SLOT_BYTES)
#define MAGIC_HI 0x5EEDu        // flag = (MAGIC_HI<<16)|count ; poison=0xAAAA....
#define POLL_MAX 2048

__global__ __launch_bounds__(512) void k_all(const float* __restrict__ img,
                                             float* __restrict__ out,
                                             unsigned char* __restrict__ ws) {
    __shared__ unsigned short slist[SEED_CAP];
    __shared__ unsigned short plist[512];
    __shared__ unsigned char sd[RGSZ + 4];
    __shared__ int scount, pcount, missCount;
    __shared__ unsigned char missSeg[128];

    const int t  = threadIdx.x;         // 0..511
    const int b  = blockIdx.x;          // 0..255
    const int n  = b >> 7;              // image 0/1
    const int pr = b & 127;             // 16 tile-rows x 8 pairs
    const int y0 = (pr >> 3) << 4;      // region top row
    const int x0 = (pr & 7)  << 5;      // region left col (32-wide)

    if (t == 0) { scount = 0; pcount = 0; missCount = 0; }
    __syncthreads();

    // ---- Producer: scan own 512-px segment (global pixels [b*512,b*512+512)).
    // One coalesced uint4 load per thread (t<128). Inputs are exactly 0/1, so
    // the integer-bit nonzero test is exact. Image-1 global pixel indices wrap
    // mod 2^16 in the ushort, which IS the local (y<<8|x) index (65536==2^16).
    if (t < 128) {
        const uint4 v = reinterpret_cast<const uint4*>(img)[(b << 7) + t];
        if (v.x | v.y | v.z | v.w) {             // rare (~66 hits / image)
            const int gp = ((b << 7) + t) << 2;  // global pixel index
            if (v.x) { const int i = atomicAdd(&pcount, 1); if (i < 512) plist[i] = (unsigned short)(gp + 0); }
            if (v.y) { const int i = atomicAdd(&pcount, 1); if (i < 512) plist[i] = (unsigned short)(gp + 1); }
            if (v.z) { const int i = atomicAdd(&pcount, 1); if (i < 512) plist[i] = (unsigned short)(gp + 2); }
            if (v.w) { const int i = atomicAdd(&pcount, 1); if (i < 512) plist[i] = (unsigned short)(gp + 3); }
        }
    }
    __syncthreads();
    {
        const int pc = min(pcount, 512);         // structurally <= 512 anyway
        unsigned short* slot = reinterpret_cast<unsigned short*>(ws + b * SLOT_BYTES);
        for (int i = t; i < pc; i += 512) slot[i] = plist[i];
        __syncthreads();                         // slot writes done block-wide
        if (t == 0) {
            __threadfence();                     // publish slot before flag
            __hip_atomic_store(reinterpret_cast<unsigned int*>(ws + FLAGS_OFF) + b,
                               (MAGIC_HI << 16) | (unsigned int)pc,
                               __ATOMIC_RELEASE, __HIP_MEMORY_SCOPE_AGENT);
        }
    }

    // ---- Consumer: gather this image's 128 segment slots into LDS seed list.
    unsigned int* flags = reinterpret_cast<unsigned int*>(ws + FLAGS_OFF);
    const int segBase = n << 7;
    if (t < 128) {
        const int fb = segBase + t;              // 0..255
        unsigned int f = 0;
        int ok = 0;
        for (int sp = 0; sp < POLL_MAX; ++sp) {
            f = __hip_atomic_load(&flags[fb], __ATOMIC_ACQUIRE,
                                  __HIP_MEMORY_SCOPE_AGENT);
            if ((f >> 16) == MAGIC_HI) { ok = 1; break; }
            __builtin_amdgcn_s_sleep(2);
        }
        if (ok) {
            const int c = min((int)(f & 0xFFFFu), 512);  // clamped: no OOB possible
            if (c > 0) {
                const unsigned short* sl =
                    reinterpret_cast<const unsigned short*>(ws + fb * SLOT_BYTES);
                const int base_ = atomicAdd(&scount, c); // <= 128*512: no overflow
                for (int i = 0; i < c; ++i) {
                    const int d_ = base_ + i;
                    if (d_ < SEED_CAP) slist[d_] = sl[i];
                }
            }
        } else {
            const int mi = atomicAdd(&missCount, 1);
            if (mi < 128) missSeg[mi] = (unsigned char)t;
        }
    }
    __syncthreads();
    // Rare fallback: self-scan any unready segment (2 KB each, 1 px/thread).
    {
        const int mc = min(missCount, 128);      // uniform (read after barrier)
        for (int m = 0; m < mc; ++m) {
            const int seg = segBase + missSeg[m];
            const float x = img[(seg << 9) + t];
            if (x != 0.0f) {
                const int i = atomicAdd(&scount, 1);
                if (i < SEED_CAP)
                    slist[i] = (unsigned short)((unsigned)((seg << 9) + t) & 0xFFFFu);
            }
        }
    }
    __syncthreads();
    const int cnt = min(scount, SEED_CAP);

    // ---- Chebyshev distance for the 18x34 region (clamped coords =>
    // replicate-pad semantics). Chain A: cells 0..511 (all threads).
    {
        const int ry = t / RGX, rx = t - ry * RGX;
        const int gy = min(max(y0 - 1 + ry, 0), 255);
        const int gx = min(max(x0 - 1 + rx, 0), 255);
        int best = 1023;
        for (int s = 0; s < cnt; ++s) {
            const int sp = slist[s];             // wave-uniform broadcast
            const int sy = sp >> 8;
            const int sx = sp & 255;
            int dy = gy - sy; dy = (dy < 0) ? -dy : dy;
            int dx = gx - sx; dx = (dx < 0) ? -dx : dx;
            best = min(best, max(dy, dx));
        }
        sd[t] = (unsigned char)best;
    }
    // Chain B: cells 512..611, threads 0..99 only (other waves skip via execz).
    if (t < RGSZ - 512) {
        const int r  = t + 512;
        const int ry = r / RGX, rx = r - ry * RGX;
        const int gy = min(max(y0 - 1 + ry, 0), 255);
        const int gx = min(max(x0 - 1 + rx, 0), 255);
        int best = 1023;
        for (int s = 0; s < cnt; ++s) {
            const int sp = slist[s];
            const int sy = sp >> 8;
            const int sx = sp & 255;
            int dy = gy - sy; dy = (dy < 0) ? -dy : dy;
            int dx = gx - sx; dx = (dx < 0) ? -dx : dx;
            best = min(best, max(dy, dx));
        }
        sd[r] = (unsigned char)best;
    }
    __syncthreads();

    // ---- Epilogue, one output pixel per thread (identical math to the
    // absmax=0.0-verified rounds).
    const float W1 = expf(-(1.0f / 0.35f));
    const float W2 = expf(-(1.41421356f / 0.35f));
    const int oy = t >> 5;
    const int ox = t & 31;
    const int rc = (oy + 1) * RGX + (ox + 1);
    const int dp = sd[rc];
    const int a =
        (sd[rc - RGX] < dp) + (sd[rc + RGX] < dp) +
        (sd[rc - 1  ] < dp) + (sd[rc + 1  ] < dp);
    const int c =
        (sd[rc - RGX - 1] < dp) + (sd[rc - RGX + 1] < dp) +
        (sd[rc + RGX - 1] < dp) + (sd[rc + RGX + 1] < dp);
    const float S = (float)a * W1 + (float)c * W2;   // > 0 whenever dp > 0
    const float v = (float)(dp - 1) - 0.35f * logf(S);
    out[(n << 16) + ((y0 + oy) << 8) + (x0 + ox)] = (dp > 0) ? v : 0.0f;
}

extern "C" void kernel_launch(void* const* d_in, const int* in_sizes, int n_in,
                              void* d_out, int out_size, void* d_ws, size_t ws_size,
                              hipStream_t stream) {
    (void)in_sizes; (void)n_in; (void)out_size; (void)ws_size;
    const float* img = (const float*)d_in[0];
    float* out = (float*)d_out;
    unsigned char* ws = (unsigned char*)d_ws;
    k_all<<<NBLK, 512, 0, stream>>>(img, out, ws);
}

// Round 6
// 58.401 us; speedup vs baseline: 1.2619x; 1.2619x over previous
//
#include <hip/hip_runtime.h>

// DistanceTransform closed form (verified absmax=0.0 in earlier rounds):
//   d(p)  = Chebyshev (L_inf) distance to nearest seed (replicate-pad => clamp)
//   out(p)= 0 if d==0 else (d-1) - 0.35*log(a*w1 + c*w2)
// where a/c = # edge/corner 3x3 taps whose CLAMPED source pixel has d < d(p),
// w1 = exp(-1/0.35), w2 = exp(-sqrt(2)/0.35).
//
// FINAL structure (= round-6, measured 58.3us; fastest of all variants):
//   two-kernel bitmap pipeline. Fusion alternatives measured WORSE:
//   every-block-scans 64.2us, producer/consumer ws-flag spin 73.7us (cross-XCD
//   release-store visibility is serialized per block; a kernel boundary does
//   the same drain once, globally, cheaper).
//   - k_seed: one pass over input -> 8 KB/image seed BITMAP in ws (full
//     overwrite, so the 0xAA-poisoned ws needs no init, no atomics)
//   - k_main: 256 blocks x 512 threads, one 16x32 pair-region per block
//     (halves bitmap traffic + chain-iters vs 16x16 tiles), bitmap read as
//     ONE uint4 per thread, chain B exec-masked to threads 0..99,
//     1 output pixel per thread in the fused epilogue.

#define RGX 34                  // 32 + 2 halo
#define RGY 18                  // 16 + 2 halo
#define RGSZ (RGX * RGY)        // 612
#define SEED_CAP 1024

// ---- Kernel 1: build seed bitmap (1 bit per pixel, 8 KB per image) ----
__global__ __launch_bounds__(256) void k_seed(const float* __restrict__ img,
                                              unsigned short* __restrict__ bm) {
    const int g = blockIdx.x * 256 + threadIdx.x;   // 0..8191
    const int n = g >> 12;                          // image
    const int h = g & 4095;                         // 16-pixel group
    const float4* p = reinterpret_cast<const float4*>(img + (n << 16) + (h << 4));
    unsigned int m = 0;
    #pragma unroll
    for (int q = 0; q < 4; ++q) {
        const float4 v = p[q];
        m |= (unsigned int)(v.x != 0.0f) << (q * 4 + 0);
        m |= (unsigned int)(v.y != 0.0f) << (q * 4 + 1);
        m |= (unsigned int)(v.z != 0.0f) << (q * 4 + 2);
        m |= (unsigned int)(v.w != 0.0f) << (q * 4 + 3);
    }
    bm[g] = (unsigned short)m;                      // full overwrite of ws region
}

// ---- Kernel 2: extract seeds, Chebyshev DT per 16x32 pair-region, epilogue ----
__global__ __launch_bounds__(512) void k_main(const unsigned short* __restrict__ bm,
                                              float* __restrict__ out) {
    __shared__ unsigned short slist[SEED_CAP];
    __shared__ int scount;
    __shared__ unsigned char sd[RGSZ + 4];

    const int t  = threadIdx.x;         // 0..511
    const int b  = blockIdx.x;          // 0..255
    const int n  = b >> 7;              // image 0/1
    const int pr = b & 127;             // 16 tile-rows x 8 pairs
    const int y0 = (pr >> 3) << 4;      // region top row
    const int x0 = (pr & 7)  << 5;      // region left col (32-wide)

    if (t == 0) scount = 0;
    __syncthreads();

    // Phase 1: bitmap (2048 uint words per image, L2-hot) -> LDS seed list.
    // One coalesced uint4 load per thread covers the whole 8 KB bitmap.
    {
        const uint4* w4 = reinterpret_cast<const uint4*>(bm) + (n << 9);
        const uint4 v = w4[t];
        const unsigned int wv[4] = { v.x, v.y, v.z, v.w };
        #pragma unroll
        for (int j = 0; j < 4; ++j) {
            unsigned int m = wv[j];
            const int wbase = ((t << 2) + j) << 5;   // pixel index of bit 0
            while (m) {                               // ~66 set bits per image
                const int bit = __ffs(m) - 1;
                m &= m - 1;
                const int i_ = atomicAdd(&scount, 1);
                if (i_ < SEED_CAP) slist[i_] = (unsigned short)(wbase + bit);
            }
        }
    }
    __syncthreads();
    const int cnt = min(scount, SEED_CAP);

    // Phase 2: Chebyshev distance for the 18x34 region (clamped coords =>
    // replicate-pad semantics). Chain A: cells 0..511 (all threads).
    {
        const int ry = t / RGX, rx = t - ry * RGX;
        const int gy = min(max(y0 - 1 + ry, 0), 255);
        const int gx = min(max(x0 - 1 + rx, 0), 255);
        int best = 1023;
        for (int s = 0; s < cnt; ++s) {
            const int sp = slist[s];                 // wave-uniform broadcast
            const int sy = sp >> 8;
            const int sx = sp & 255;
            int dy = gy - sy; dy = (dy < 0) ? -dy : dy;
            int dx = gx - sx; dx = (dx < 0) ? -dx : dx;
            best = min(best, max(dy, dx));
        }
        sd[t] = (unsigned char)best;
    }
    // Chain B: cells 512..611, threads 0..99 only (waves 2..7 skip via execz).
    if (t < RGSZ - 512) {
        const int r  = t + 512;
        const int ry = r / RGX, rx = r - ry * RGX;
        const int gy = min(max(y0 - 1 + ry, 0), 255);
        const int gx = min(max(x0 - 1 + rx, 0), 255);
        int best = 1023;
        for (int s = 0; s < cnt; ++s) {
            const int sp = slist[s];
            const int sy = sp >> 8;
            const int sx = sp & 255;
            int dy = gy - sy; dy = (dy < 0) ? -dy : dy;
            int dx = gx - sx; dx = (dx < 0) ? -dx : dx;
            best = min(best, max(dy, dx));
        }
        sd[r] = (unsigned char)best;
    }
    __syncthreads();

    // Phase 3: epilogue, one output pixel per thread (identical math to the
    // absmax=0.0-verified rounds).
    const float W1 = expf(-(1.0f / 0.35f));
    const float W2 = expf(-(1.41421356f / 0.35f));
    const int oy = t >> 5;
    const int ox = t & 31;
    const int rc = (oy + 1) * RGX + (ox + 1);
    const int dp = sd[rc];
    const int a =
        (sd[rc - RGX] < dp) + (sd[rc + RGX] < dp) +
        (sd[rc - 1  ] < dp) + (sd[rc + 1  ] < dp);
    const int c =
        (sd[rc - RGX - 1] < dp) + (sd[rc - RGX + 1] < dp) +
        (sd[rc + RGX - 1] < dp) + (sd[rc + RGX + 1] < dp);
    const float S = (float)a * W1 + (float)c * W2;   // > 0 whenever dp > 0
    const float v = (float)(dp - 1) - 0.35f * logf(S);
    out[(n << 16) + ((y0 + oy) << 8) + (x0 + ox)] = (dp > 0) ? v : 0.0f;
}

extern "C" void kernel_launch(void* const* d_in, const int* in_sizes, int n_in,
                              void* d_out, int out_size, void* d_ws, size_t ws_size,
                              hipStream_t stream) {
    (void)in_sizes; (void)n_in; (void)out_size; (void)ws_size;
    const float* img = (const float*)d_in[0];
    float* out = (float*)d_out;
    unsigned short* bm = (unsigned short*)d_ws;      // 16 KB bitmap (2 images)
    k_seed<<<32, 256, 0, stream>>>(img, bm);
    k_main<<<256, 512, 0, stream>>>(bm, out);
}